// Round 4
// baseline (2074.407 us; speedup 1.0000x reference)
//
#include <hip/hip_runtime.h>

#define NBLKA 2048

__device__ __forceinline__ unsigned encf(float x) {
    unsigned u = __float_as_uint(x);
    return (u & 0x80000000u) ? ~u : (u | 0x80000000u);
}
__device__ __forceinline__ float decf(unsigned u) {
    u = (u & 0x80000000u) ? (u & 0x7FFFFFFFu) : ~u;
    return __uint_as_float(u);
}

// ============ CSR build: deterministic matrix-scan counting sort ============

__global__ __launch_bounds__(256) void passA_k(const int* __restrict__ dst, int E,
                                               int* __restrict__ cntMat, int shift,
                                               int nblk, int nbUsed) {
    __shared__ int hist[256];
    hist[threadIdx.x] = 0;
    __syncthreads();
    int base = blockIdx.x * 4096;
#pragma unroll
    for (int r = 0; r < 16; r++) {
        int i = base + threadIdx.x + r * 256;
        if (i < E) atomicAdd(&hist[dst[i] >> shift], 1);
    }
    __syncthreads();
    if (threadIdx.x < nbUsed) cntMat[threadIdx.x * nblk + blockIdx.x] = hist[threadIdx.x];
}

// ---------- generic 3-kernel inclusive scan ----------
__global__ void scanA_k(int* __restrict__ data, int total, int* __restrict__ chunkTot) {
    __shared__ int sd[256];
    int tid = threadIdx.x;
    int base = blockIdx.x * 2048 + tid * 8;
    int v[8]; int s = 0;
#pragma unroll
    for (int r = 0; r < 8; r++) {
        int idx = base + r;
        int x = (idx < total) ? data[idx] : 0;
        s += x; v[r] = s;
    }
    sd[tid] = s; __syncthreads();
    for (int off = 1; off < 256; off <<= 1) {
        int x = (tid >= off) ? sd[tid - off] : 0;
        __syncthreads();
        sd[tid] += x;
        __syncthreads();
    }
    int prev = (tid > 0) ? sd[tid - 1] : 0;
#pragma unroll
    for (int r = 0; r < 8; r++) {
        int idx = base + r;
        if (idx < total) data[idx] = v[r] + prev;
    }
    if (tid == 255) chunkTot[blockIdx.x] = sd[255];
}

__global__ void scanB_k(const int* __restrict__ chunkTot, int nchunk, int* __restrict__ chunkOff) {
    __shared__ int sd[256];
    int tid = threadIdx.x;
    int v = (tid < nchunk) ? chunkTot[tid] : 0;
    sd[tid] = v; __syncthreads();
    for (int off = 1; off < 256; off <<= 1) {
        int x = (tid >= off) ? sd[tid - off] : 0;
        __syncthreads();
        sd[tid] += x;
        __syncthreads();
    }
    if (tid < nchunk) chunkOff[tid] = sd[tid] - v;
}

__global__ void scanC2_k(int* __restrict__ data, int total, const int* __restrict__ chunkOff) {
    int off = chunkOff[blockIdx.x];
    int base = blockIdx.x * 2048 + threadIdx.x * 8;
#pragma unroll
    for (int r = 0; r < 8; r++) {
        int idx = base + r;
        if (idx < total) data[idx] += off;
    }
}

// pass B: LDS counting sort of 4096 edges into bucket-grouped 4B entries
__global__ __launch_bounds__(256) void passB_k(const int* __restrict__ ei,
                                               const int* __restrict__ ety, int E,
                                               const int* __restrict__ cntScan,
                                               unsigned* __restrict__ binned,
                                               int shift, int sBits, int nblk, int nbUsed) {
    __shared__ unsigned stage[4096];
    __shared__ int bkid[4096];
    __shared__ int hist[256], sd[256], cursor[256], rebase[256];
    int tid = threadIdx.x;
    int base = blockIdx.x * 4096;
    hist[tid] = 0;
    __syncthreads();

    unsigned ent[16];
    int bk[16];
    int lowmask = (1 << shift) - 1;
#pragma unroll
    for (int r = 0; r < 16; r++) {
        int i = base + tid + r * 256;
        if (i < E) {
            int s = ei[i];
            int d = ei[E + i];
            int t = ety[i];
            ent[r] = ((unsigned)(d & lowmask) << (sBits + 1)) | ((unsigned)t << sBits) | (unsigned)s;
            bk[r] = d >> shift;
            atomicAdd(&hist[bk[r]], 1);
        } else bk[r] = -1;
    }
    __syncthreads();

    int h = hist[tid];
    sd[tid] = h; __syncthreads();
    for (int off = 1; off < 256; off <<= 1) {
        int x = (tid >= off) ? sd[tid - off] : 0;
        __syncthreads();
        sd[tid] += x;
        __syncthreads();
    }
    int excl = sd[tid] - h;
    cursor[tid] = excl;
    int gb = 0;
    if (tid < nbUsed && h > 0) gb = cntScan[tid * nblk + blockIdx.x] - h;
    rebase[tid] = gb - excl;
    __syncthreads();

#pragma unroll
    for (int r = 0; r < 16; r++) {
        if (bk[r] >= 0) {
            int p = atomicAdd(&cursor[bk[r]], 1);
            stage[p] = ent[r];
            bkid[p] = bk[r];
        }
    }
    __syncthreads();

    int cnt = E - base; if (cnt > 4096) cnt = 4096;
    for (int i = tid; i < cnt; i += 256)
        binned[rebase[bkid[i]] + i] = stage[i];
}

// pass C: per-bucket LDS counting sort, fused rowptr, coalesced final writes
__global__ __launch_bounds__(256) void passC_k(const unsigned* __restrict__ binned,
                                               const int* __restrict__ cntScan,
                                               int nblk, int* __restrict__ rowptr,
                                               unsigned* __restrict__ sorted,
                                               int N, int E, int shift, int sBits,
                                               int nbUsed) {
    __shared__ unsigned stage[12288];
    __shared__ int hist[512], cursor[512], sd[256];
    int tid = threadIdx.x;
    int b = blockIdx.x;
    int s = (b == 0) ? 0 : cntScan[b * nblk - 1];
    int e = cntScan[(b + 1) * nblk - 1];
    int nodeBase = b << shift;
    int half = 1 << (shift - 1);
    int dshift = sBits + 1;
    int segBase = s;

    for (int ph = 0; ph < 2; ph++) {
        int lnBase = ph * half;
        hist[tid] = 0; hist[tid + 256] = 0;
        __syncthreads();
        for (int i = s + tid; i < e; i += 256) {
            int ln = (int)(binned[i] >> dshift) - lnBase;
            if (ln >= 0 && ln < half) atomicAdd(&hist[ln], 1);
        }
        __syncthreads();
        int v0 = hist[2 * tid], v1 = hist[2 * tid + 1];
        int sum2 = v0 + v1;
        sd[tid] = sum2; __syncthreads();
        for (int off = 1; off < 256; off <<= 1) {
            int x = (tid >= off) ? sd[tid - off] : 0;
            __syncthreads();
            sd[tid] += x;
            __syncthreads();
        }
        int exclPair = sd[tid] - sum2;
        int total = sd[255];
        __syncthreads();
        hist[2 * tid] = exclPair;
        hist[2 * tid + 1] = exclPair + v0;
        cursor[2 * tid] = exclPair;
        cursor[2 * tid + 1] = exclPair + v0;
        __syncthreads();
        for (int i = s + tid; i < e; i += 256) {
            unsigned en = binned[i];
            int ln = (int)(en >> dshift) - lnBase;
            if (ln >= 0 && ln < half) {
                int p = atomicAdd(&cursor[ln], 1);
                if (p < 12288) stage[p] = en;
            }
        }
        __syncthreads();
        for (int k = tid; k < total; k += 256)
            if (k < 12288) sorted[segBase + k] = stage[k];
        for (int i = tid; i < half; i += 256) {
            int n = nodeBase + lnBase + i;
            if (n < N) rowptr[n] = segBase + hist[i];
        }
        segBase += total;
        __syncthreads();
    }
    if (b == nbUsed - 1 && tid == 0) rowptr[N] = E;
}

__global__ void initpool_k(unsigned* __restrict__ maxb, float* __restrict__ sumb, int n) {
    int i = blockIdx.x * blockDim.x + threadIdx.x;
    if (i < n) { maxb[i] = 0x007FFFFFu; sumb[i] = 0.f; }  // enc(-inf)
}

// ---------- layer A: wave-per-node aggregate + z@W1+b1 + BN partials ----------
__global__ __launch_bounds__(256) void layerA_k(
    const float* __restrict__ hin, const int* __restrict__ rowptr,
    const unsigned* __restrict__ sorted, const float* __restrict__ emb,
    const float* __restrict__ W1, const float* __restrict__ b1,
    float* __restrict__ tout, float* __restrict__ partial, int Nn, int sBits)
{
    int tid = threadIdx.x;
    int lane = tid & 63;
    int j = lane & 31;          // channel
    int hf = lane >> 5;         // edge parity
    int wid = (blockIdx.x * blockDim.x + tid) >> 6;
    int nW = (gridDim.x * blockDim.x) >> 6;
    unsigned smask = (1u << sBits) - 1u;

    float w1c[32];
#pragma unroll
    for (int k = 0; k < 32; k++) w1c[k] = W1[k * 32 + j];
    float b1j = b1[j];
    float e0v = emb[j], e1v = emb[32 + j];
    float bsum = 0.f, bsq = 0.f;

    for (int n = wid; n < Nn; n += nW) {
        int es = rowptr[n], ee = rowptr[n + 1];
        float acc = (hf == 0) ? hin[(unsigned)n * 32u + (unsigned)j] : 0.f;
        float acc2 = 0.f;
        int e = es + hf;
        for (; e + 2 < ee; e += 4) {
            unsigned p0 = sorted[e];
            unsigned p1 = sorted[e + 2];
            unsigned o0 = (p0 & smask) * 32u + (unsigned)j;
            unsigned o1 = (p1 & smask) * 32u + (unsigned)j;
            float h0 = hin[o0];
            float h1 = hin[o1];
            float v0 = ((p0 >> sBits) & 1u) ? e1v : e0v;
            float v1 = ((p1 >> sBits) & 1u) ? e1v : e0v;
            acc  += fmaxf(h0 + v0, 0.f);
            acc2 += fmaxf(h1 + v1, 0.f);
        }
        for (; e < ee; e += 2) {
            unsigned p = sorted[e];
            unsigned o = (p & smask) * 32u + (unsigned)j;
            float hs = hin[o];
            float ev = ((p >> sBits) & 1u) ? e1v : e0v;
            acc += fmaxf(hs + ev, 0.f);
        }
        acc += acc2;
        acc += __shfl_xor(acc, 32);    // combine halves: full z_j in every lane

        float t0 = b1j, t1 = 0.f;
#pragma unroll
        for (int k = 0; k < 32; k += 2) {
            t0 = fmaf(__shfl(acc, k), w1c[k], t0);
            t1 = fmaf(__shfl(acc, k + 1), w1c[k + 1], t1);
        }
        float t = t0 + t1;
        if (hf == 0) tout[(unsigned)n * 32u + (unsigned)j] = t;
        bsum += t; bsq += t * t;   // duplicated in hf==1; reduce uses hf==0 only
    }

    __shared__ float ls[4][32], lq[4][32];
    if (hf == 0) { ls[tid >> 6][j] = bsum; lq[tid >> 6][j] = bsq; }
    __syncthreads();
    if (tid < 32) {
        float s = ls[0][tid] + ls[1][tid] + ls[2][tid] + ls[3][tid];
        float q = lq[0][tid] + lq[1][tid] + lq[2][tid] + lq[3][tid];
        partial[blockIdx.x * 64 + tid] = s;
        partial[blockIdx.x * 64 + 32 + tid] = q;
    }
}

// ---------- BN stat reduce -> a, c ----------
__global__ void bnred_k(const float* __restrict__ partial, int nblk,
                        const float* __restrict__ gamma, const float* __restrict__ beta,
                        float* __restrict__ bn_ac, float invN)
{
    __shared__ float sd[256];
    __shared__ float tot[64];
    int tid = threadIdx.x;
    int j = tid >> 2, sub = tid & 3;
    float s = 0.f;
    for (int b = sub; b < nblk; b += 4) s += partial[b * 64 + j];
    sd[tid] = s; __syncthreads();
    if (sub == 0) tot[j] = sd[tid] + sd[tid + 1] + sd[tid + 2] + sd[tid + 3];
    __syncthreads();
    if (tid < 32) {
        float mu = tot[tid] * invN;
        float var = tot[32 + tid] * invN - mu * mu;
        float a = gamma[tid] * rsqrtf(var + 1e-5f);
        bn_ac[tid] = a;
        bn_ac[32 + tid] = beta[tid] - a * mu;
    }
}

// ---------- layer B: relu(bn(t)) @ W2 + b2 (+relu) ----------
__global__ __launch_bounds__(256) void layerB32_k(
    const float* __restrict__ tin, const float* __restrict__ bn_ac,
    const float* __restrict__ W2, const float* __restrict__ b2,
    float* __restrict__ hout, int Nn, int doRelu)
{
    int tid = threadIdx.x;
    int j = tid & 31, grp = tid >> 5;
    float a = bn_ac[j], c = bn_ac[32 + j];
    float wc[32];
#pragma unroll
    for (int k = 0; k < 32; k++) wc[k] = W2[k * 32 + j];
    float bj = b2[j];
    for (int n = blockIdx.x * 8 + grp; n < Nn; n += gridDim.x * 8) {
        float t = tin[n * 32 + j];
        float u = fmaxf(fmaf(a, t, c), 0.f);
        float o = bj;
#pragma unroll
        for (int k = 0; k < 32; k++) o = fmaf(__shfl(u, k, 32), wc[k], o);
        hout[n * 32 + j] = doRelu ? fmaxf(o, 0.f) : o;
    }
}

__global__ __launch_bounds__(256) void layerB64_k(
    const float* __restrict__ tin, const float* __restrict__ bn_ac,
    const float* __restrict__ W2, const float* __restrict__ b2,
    float* __restrict__ hout, int Nn)
{
    int tid = threadIdx.x;
    int j = tid & 31, grp = tid >> 5;
    float a = bn_ac[j], c = bn_ac[32 + j];
    float wlo[32], whi[32];
#pragma unroll
    for (int k = 0; k < 32; k++) { wlo[k] = W2[k * 64 + j]; whi[k] = W2[k * 64 + 32 + j]; }
    float blo = b2[j], bhi = b2[32 + j];
    for (int n = blockIdx.x * 8 + grp; n < Nn; n += gridDim.x * 8) {
        float t = tin[n * 32 + j];
        float u = fmaxf(fmaf(a, t, c), 0.f);
        float olo = blo, ohi = bhi;
#pragma unroll
        for (int k = 0; k < 32; k++) {
            float uk = __shfl(u, k, 32);
            olo = fmaf(uk, wlo[k], olo);
            ohi = fmaf(uk, whi[k], ohi);
        }
        hout[n * 64 + j] = olo;
        hout[n * 64 + 32 + j] = ohi;
    }
}

// ---------- pooling ----------
__global__ void pool1_k(const float* __restrict__ h5, const int* __restrict__ batch,
                        unsigned* __restrict__ maxb, float* __restrict__ sumb, int Nn)
{
    int ch = threadIdx.x & 63, slot = threadIdx.x >> 6;
    int base = blockIdx.x * 256 + slot * 64;
    int g = -1; float mx = 0.f, sm = 0.f;
    for (int i = 0; i < 64; i++) {
        int node = base + i;
        if (node >= Nn) break;
        int gn = batch[node];
        float v = h5[node * 64 + ch];
        if (gn != g) {
            if (g >= 0) { atomicMax(&maxb[g * 64 + ch], encf(mx)); atomicAdd(&sumb[g * 64 + ch], sm); }
            g = gn; mx = v; sm = v;
        } else { mx = fmaxf(mx, v); sm += v; }
    }
    if (g >= 0) { atomicMax(&maxb[g * 64 + ch], encf(mx)); atomicAdd(&sumb[g * 64 + ch], sm); }
}

__global__ void final_k(const unsigned* __restrict__ maxb, const float* __restrict__ sumb,
                        const int* __restrict__ batch, int Nn, float* __restrict__ out)
{
    int g = blockIdx.x, tid = threadIdx.x;
    int a = 0, b = Nn;
    while (a < b) { int m = (a + b) >> 1; if (batch[m] < g) a = m + 1; else b = m; }
    int lo0 = a;
    a = 0; b = Nn;
    while (a < b) { int m = (a + b) >> 1; if (batch[m] < g + 1) a = m + 1; else b = m; }
    int hi0 = a;
    float inv = 1.f / fmaxf((float)(hi0 - lo0), 1.f);
    if (tid < 64) out[g * 128 + tid] = decf(maxb[g * 64 + tid]);
    else          out[g * 128 + tid] = sumb[g * 64 + (tid - 64)] * inv;
}

extern "C" void kernel_launch(void* const* d_in, const int* in_sizes, int n_in,
                              void* d_out, int out_size, void* d_ws, size_t ws_size,
                              hipStream_t stream) {
    const float* x    = (const float*)d_in[0];
    const int*   ei   = (const int*)d_in[1];
    const int*   ety  = (const int*)d_in[2];
    const int*   batch= (const int*)d_in[3];
    const float* emb  = (const float*)d_in[4];
    const float* W1s  = (const float*)d_in[5];
    const float* b1s  = (const float*)d_in[6];
    const float* g1s  = (const float*)d_in[7];
    const float* be1s = (const float*)d_in[8];
    const float* W2s  = (const float*)d_in[9];
    const float* b2s  = (const float*)d_in[10];
    const float* w15  = (const float*)d_in[11];
    const float* b15  = (const float*)d_in[12];
    const float* g5   = (const float*)d_in[13];
    const float* be5  = (const float*)d_in[14];
    const float* w25  = (const float*)d_in[15];
    const float* b25  = (const float*)d_in[16];

    int N = in_sizes[0] / 32;
    int E = in_sizes[1] / 2;
    int G = out_size / 128;

    int sBits = 1; while ((1 << sBits) < N) sBits++;               // 18 for N=200k
    int shift = 0; while (((N - 1) >> shift) >= 256) shift++;      // 10
    int nbUsed = ((N - 1) >> shift) + 1;                           // 196
    int nblkE = (E + 4095) / 4096;                                 // 977

    char* wsb = (char*)d_ws;
    size_t o = 0;
    size_t h5Bytes = (size_t)N * 64 * 4;
    size_t binBytes = (size_t)E * 4;
    size_t aliasBytes = h5Bytes > binBytes ? h5Bytes : binBytes;
    float*    h5     = (float*)(wsb + o);
    unsigned* binned = (unsigned*)(wsb + o);   // alias: dead before first h5 write
    o += aliasBytes;
    float*    tb     = (float*)(wsb + o); o += (size_t)N * 32 * 4;
    int*      rowptr = (int*)(wsb + o);   o += ((size_t)N + 2) * 4;
    unsigned* sorted = (unsigned*)(wsb + o); o += (size_t)E * 4;
    int*      chunkTot = (int*)(wsb + o); o += 1024;
    int*      chunkOff = (int*)(wsb + o); o += 1024;
    float*    partial  = (float*)(wsb + o); o += (size_t)NBLKA * 64 * 4;
    float*    bn_ac    = (float*)(wsb + o); o += 64 * 4;
    unsigned* maxb     = (unsigned*)(wsb + o); o += (size_t)G * 64 * 4;
    float*    sumb     = (float*)(wsb + o); o += (size_t)G * 64 * 4;
    int*      cntMat   = (int*)(wsb + o); o += (size_t)nbUsed * nblkE * 4;

    // ---- CSR build ----
    passA_k<<<nblkE, 256, 0, stream>>>(ei + E, E, cntMat, shift, nblkE, nbUsed);
    int total2 = nbUsed * nblkE;
    int nchunk2 = (total2 + 2047) / 2048;
    scanA_k<<<nchunk2, 256, 0, stream>>>(cntMat, total2, chunkTot);
    scanB_k<<<1, 256, 0, stream>>>(chunkTot, nchunk2, chunkOff);
    scanC2_k<<<nchunk2, 256, 0, stream>>>(cntMat, total2, chunkOff);
    passB_k<<<nblkE, 256, 0, stream>>>(ei, ety, E, cntMat, binned, shift, sBits, nblkE, nbUsed);
    passC_k<<<nbUsed, 256, 0, stream>>>(binned, cntMat, nblkE, rowptr, sorted, N, E, shift, sBits, nbUsed);
    initpool_k<<<(G * 64 + 255) / 256, 256, 0, stream>>>(maxb, sumb, G * 64);

    // ---- 5 GINE layers ----
    const float* hin = x;
    for (int L = 0; L < 5; ++L) {
        const float* W1 = (L < 4) ? W1s + L * 1024 : w15;
        const float* b1 = (L < 4) ? b1s + L * 32  : b15;
        const float* ga = (L < 4) ? g1s + L * 32  : g5;
        const float* be = (L < 4) ? be1s + L * 32 : be5;
        const float* W2 = (L < 4) ? W2s + L * 1024 : w25;
        const float* b2 = (L < 4) ? b2s + L * 32  : b25;

        layerA_k<<<NBLKA, 256, 0, stream>>>(hin, rowptr, sorted, emb, W1, b1, tb, partial, N, sBits);
        bnred_k<<<1, 256, 0, stream>>>(partial, NBLKA, ga, be, bn_ac, 1.f / (float)N);
        if (L < 4) layerB32_k<<<1024, 256, 0, stream>>>(tb, bn_ac, W2, b2, h5, N, 1);
        else       layerB64_k<<<1024, 256, 0, stream>>>(tb, bn_ac, W2, b2, h5, N);
        hin = h5;
    }

    // ---- pooling ----
    pool1_k<<<(N + 255) / 256, 256, 0, stream>>>(h5, batch, maxb, sumb, N);
    final_k<<<G, 128, 0, stream>>>(maxb, sumb, batch, N, (float*)d_out);
}

// Round 5
// 1384.360 us; speedup vs baseline: 1.4985x; 1.4985x over previous
//
#include <hip/hip_runtime.h>

#define NBLKA 2048

__device__ __forceinline__ unsigned encf(float x) {
    unsigned u = __float_as_uint(x);
    return (u & 0x80000000u) ? ~u : (u | 0x80000000u);
}
__device__ __forceinline__ float decf(unsigned u) {
    u = (u & 0x80000000u) ? (u & 0x7FFFFFFFu) : ~u;
    return __uint_as_float(u);
}

// ============ CSR build: deterministic matrix-scan counting sort ============

__global__ __launch_bounds__(256) void passA_k(const int* __restrict__ dst, int E,
                                               int* __restrict__ cntMat, int shift,
                                               int nblk, int nbUsed) {
    __shared__ int hist[256];
    hist[threadIdx.x] = 0;
    __syncthreads();
    int base = blockIdx.x * 4096;
#pragma unroll
    for (int r = 0; r < 16; r++) {
        int i = base + threadIdx.x + r * 256;
        if (i < E) atomicAdd(&hist[dst[i] >> shift], 1);
    }
    __syncthreads();
    if (threadIdx.x < nbUsed) cntMat[threadIdx.x * nblk + blockIdx.x] = hist[threadIdx.x];
}

__global__ void scanA_k(int* __restrict__ data, int total, int* __restrict__ chunkTot) {
    __shared__ int sd[256];
    int tid = threadIdx.x;
    int base = blockIdx.x * 2048 + tid * 8;
    int v[8]; int s = 0;
#pragma unroll
    for (int r = 0; r < 8; r++) {
        int idx = base + r;
        int x = (idx < total) ? data[idx] : 0;
        s += x; v[r] = s;
    }
    sd[tid] = s; __syncthreads();
    for (int off = 1; off < 256; off <<= 1) {
        int x = (tid >= off) ? sd[tid - off] : 0;
        __syncthreads();
        sd[tid] += x;
        __syncthreads();
    }
    int prev = (tid > 0) ? sd[tid - 1] : 0;
#pragma unroll
    for (int r = 0; r < 8; r++) {
        int idx = base + r;
        if (idx < total) data[idx] = v[r] + prev;
    }
    if (tid == 255) chunkTot[blockIdx.x] = sd[255];
}

__global__ void scanB_k(const int* __restrict__ chunkTot, int nchunk, int* __restrict__ chunkOff) {
    __shared__ int sd[256];
    int tid = threadIdx.x;
    int v = (tid < nchunk) ? chunkTot[tid] : 0;
    sd[tid] = v; __syncthreads();
    for (int off = 1; off < 256; off <<= 1) {
        int x = (tid >= off) ? sd[tid - off] : 0;
        __syncthreads();
        sd[tid] += x;
        __syncthreads();
    }
    if (tid < nchunk) chunkOff[tid] = sd[tid] - v;
}

__global__ void scanC2_k(int* __restrict__ data, int total, const int* __restrict__ chunkOff) {
    int off = chunkOff[blockIdx.x];
    int base = blockIdx.x * 2048 + threadIdx.x * 8;
#pragma unroll
    for (int r = 0; r < 8; r++) {
        int idx = base + r;
        if (idx < total) data[idx] += off;
    }
}

__global__ __launch_bounds__(256) void passB_k(const int* __restrict__ ei,
                                               const int* __restrict__ ety, int E,
                                               const int* __restrict__ cntScan,
                                               unsigned* __restrict__ binned,
                                               int shift, int sBits, int nblk, int nbUsed) {
    __shared__ unsigned stage[4096];
    __shared__ int bkid[4096];
    __shared__ int hist[256], sd[256], cursor[256], rebase[256];
    int tid = threadIdx.x;
    int base = blockIdx.x * 4096;
    hist[tid] = 0;
    __syncthreads();

    unsigned ent[16];
    int bk[16];
    int lowmask = (1 << shift) - 1;
#pragma unroll
    for (int r = 0; r < 16; r++) {
        int i = base + tid + r * 256;
        if (i < E) {
            int s = ei[i];
            int d = ei[E + i];
            int t = ety[i];
            ent[r] = ((unsigned)(d & lowmask) << (sBits + 1)) | ((unsigned)t << sBits) | (unsigned)s;
            bk[r] = d >> shift;
            atomicAdd(&hist[bk[r]], 1);
        } else bk[r] = -1;
    }
    __syncthreads();

    int h = hist[tid];
    sd[tid] = h; __syncthreads();
    for (int off = 1; off < 256; off <<= 1) {
        int x = (tid >= off) ? sd[tid - off] : 0;
        __syncthreads();
        sd[tid] += x;
        __syncthreads();
    }
    int excl = sd[tid] - h;
    cursor[tid] = excl;
    int gb = 0;
    if (tid < nbUsed && h > 0) gb = cntScan[tid * nblk + blockIdx.x] - h;
    rebase[tid] = gb - excl;
    __syncthreads();

#pragma unroll
    for (int r = 0; r < 16; r++) {
        if (bk[r] >= 0) {
            int p = atomicAdd(&cursor[bk[r]], 1);
            stage[p] = ent[r];
            bkid[p] = bk[r];
        }
    }
    __syncthreads();

    int cnt = E - base; if (cnt > 4096) cnt = 4096;
    for (int i = tid; i < cnt; i += 256)
        binned[rebase[bkid[i]] + i] = stage[i];
}

__global__ __launch_bounds__(256) void passC_k(const unsigned* __restrict__ binned,
                                               const int* __restrict__ cntScan,
                                               int nblk, int* __restrict__ rowptr,
                                               unsigned* __restrict__ sorted,
                                               int N, int E, int shift, int sBits,
                                               int nbUsed) {
    __shared__ unsigned stage[12288];
    __shared__ int hist[512], cursor[512], sd[256];
    int tid = threadIdx.x;
    int b = blockIdx.x;
    int s = (b == 0) ? 0 : cntScan[b * nblk - 1];
    int e = cntScan[(b + 1) * nblk - 1];
    int nodeBase = b << shift;
    int half = 1 << (shift - 1);
    int dshift = sBits + 1;
    int segBase = s;

    for (int ph = 0; ph < 2; ph++) {
        int lnBase = ph * half;
        hist[tid] = 0; hist[tid + 256] = 0;
        __syncthreads();
        for (int i = s + tid; i < e; i += 256) {
            int ln = (int)(binned[i] >> dshift) - lnBase;
            if (ln >= 0 && ln < half) atomicAdd(&hist[ln], 1);
        }
        __syncthreads();
        int v0 = hist[2 * tid], v1 = hist[2 * tid + 1];
        int sum2 = v0 + v1;
        sd[tid] = sum2; __syncthreads();
        for (int off = 1; off < 256; off <<= 1) {
            int x = (tid >= off) ? sd[tid - off] : 0;
            __syncthreads();
            sd[tid] += x;
            __syncthreads();
        }
        int exclPair = sd[tid] - sum2;
        int total = sd[255];
        __syncthreads();
        hist[2 * tid] = exclPair;
        hist[2 * tid + 1] = exclPair + v0;
        cursor[2 * tid] = exclPair;
        cursor[2 * tid + 1] = exclPair + v0;
        __syncthreads();
        for (int i = s + tid; i < e; i += 256) {
            unsigned en = binned[i];
            int ln = (int)(en >> dshift) - lnBase;
            if (ln >= 0 && ln < half) {
                int p = atomicAdd(&cursor[ln], 1);
                if (p < 12288) stage[p] = en;
            }
        }
        __syncthreads();
        for (int k = tid; k < total; k += 256)
            if (k < 12288) sorted[segBase + k] = stage[k];
        for (int i = tid; i < half; i += 256) {
            int n = nodeBase + lnBase + i;
            if (n < N) rowptr[n] = segBase + hist[i];
        }
        segBase += total;
        __syncthreads();
    }
    if (b == nbUsed - 1 && tid == 0) rowptr[N] = E;
}

__global__ void initpool_k(unsigned* __restrict__ maxb, float* __restrict__ sumb, int n) {
    int i = blockIdx.x * blockDim.x + threadIdx.x;
    if (i < n) { maxb[i] = 0x007FFFFFu; sumb[i] = 0.f; }
}

// copy x into sentinel-extended buffer P; set sentinel rows of P and Q to -1e30
__global__ void copyx_k(const float* __restrict__ x, float* __restrict__ P,
                        float* __restrict__ Q, int N) {
    int i = blockIdx.x * 256 + threadIdx.x;
    int tot = N * 8;
    if (i < tot) ((float4*)P)[i] = ((const float4*)x)[i];
    if (i < 8) {
        float4 m = {-1e30f, -1e30f, -1e30f, -1e30f};
        ((float4*)P)[tot + i] = m;
        ((float4*)Q)[tot + i] = m;
    }
}

// ---------- layer A: 16 ch-lanes x 2 edge slots per 32-group ----------
__global__ __launch_bounds__(256) void layerA_k(
    const float* __restrict__ hin, const int* __restrict__ rowptr,
    const unsigned* __restrict__ sorted, const float* __restrict__ emb,
    const float* __restrict__ W1, const float* __restrict__ b1,
    float* __restrict__ tout, float* __restrict__ partial, int Nn, int sBits,
    unsigned sentw)
{
    const float2* hin2 = (const float2*)hin;
    float2* tout2 = (float2*)tout;
    int tid = threadIdx.x;
    int gl = tid & 31;          // lane within group
    int c = gl & 15;            // channel-pair index (channels 2c, 2c+1)
    int slot = gl >> 4;         // edge slot 0/1 (also k-half for matmul)
    int grp = tid >> 5;         // group within block (0..7)
    unsigned smask = (1u << sBits) - 1u;

    // weights for this slot's k-half: W1[16*slot+kk][2c..2c+1]
    float2 w1c[16];
#pragma unroll
    for (int kk = 0; kk < 16; kk++)
        w1c[kk] = *(const float2*)&W1[(16 * slot + kk) * 32 + 2 * c];
    float2 b1p = *(const float2*)&b1[2 * c];
    float2 e0p = *(const float2*)&emb[2 * c];
    float2 e1p = *(const float2*)&emb[32 + 2 * c];

    __shared__ float zl[8][32];
    __shared__ float ls[8][32], lq[8][32];

    float2 bsum = {0.f, 0.f}, bsq = {0.f, 0.f};

    int gid0 = (blockIdx.x * 256 + tid) >> 5;
    int nG = (gridDim.x * 256) >> 5;

    for (int n = gid0; n < Nn; n += nG) {
        int es = rowptr[n], ee = rowptr[n + 1];
        float accx = 0.f, accy = 0.f;
        for (int e0 = es; e0 < ee; e0 += 32) {
            int idx = e0 + gl;
            unsigned pv = (idx < ee) ? sorted[idx] : sentw;   // sentinel pads chunk
#pragma unroll
            for (int kk = 0; kk < 16; kk++) {
                unsigned p = (unsigned)__shfl((int)pv, kk, 16);  // slot s gets word 16s+kk
                unsigned s = p & smask;
                float2 h = hin2[s * 16u + (unsigned)c];
                bool t1 = ((p >> sBits) & 1u) != 0u;
                float evx = t1 ? e1p.x : e0p.x;
                float evy = t1 ? e1p.y : e0p.y;
                accx += fmaxf(h.x + evx, 0.f);
                accy += fmaxf(h.y + evy, 0.f);
            }
        }
        // combine slots, add self term -> full z pair in every lane
        accx += __shfl_xor(accx, 16);
        accy += __shfl_xor(accy, 16);
        float2 hn = hin2[(unsigned)n * 16u + (unsigned)c];
        accx += hn.x; accy += hn.y;

        // publish z to LDS (slot0 lanes), then matmul with k-half split
        if (slot == 0) { zl[grp][2 * c] = accx; zl[grp][2 * c + 1] = accy; }
        float tx = 0.f, ty = 0.f;
#pragma unroll
        for (int kk = 0; kk < 16; kk++) {
            float zk = zl[grp][16 * slot + kk];
            tx = fmaf(zk, w1c[kk].x, tx);
            ty = fmaf(zk, w1c[kk].y, ty);
        }
        tx += __shfl_xor(tx, 16);
        ty += __shfl_xor(ty, 16);
        tx += b1p.x; ty += b1p.y;
        if (slot == 0) { float2 tp; tp.x = tx; tp.y = ty; tout2[(unsigned)n * 16u + (unsigned)c] = tp; }
        bsum.x += tx; bsum.y += ty;
        bsq.x = fmaf(tx, tx, bsq.x);
        bsq.y = fmaf(ty, ty, bsq.y);
    }

    if (slot == 0) {
        ls[grp][2 * c] = bsum.x; ls[grp][2 * c + 1] = bsum.y;
        lq[grp][2 * c] = bsq.x;  lq[grp][2 * c + 1] = bsq.y;
    }
    __syncthreads();
    if (tid < 32) {
        float s = 0.f, q = 0.f;
#pragma unroll
        for (int r = 0; r < 8; r++) { s += ls[r][tid]; q += lq[r][tid]; }
        partial[blockIdx.x * 64 + tid] = s;
        partial[blockIdx.x * 64 + 32 + tid] = q;
    }
}

// ---------- BN stat reduce -> a, c ----------
__global__ void bnred_k(const float* __restrict__ partial, int nblk,
                        const float* __restrict__ gamma, const float* __restrict__ beta,
                        float* __restrict__ bn_ac, float invN)
{
    __shared__ float sd[256];
    __shared__ float tot[64];
    int tid = threadIdx.x;
    int j = tid >> 2, sub = tid & 3;
    float s = 0.f;
    for (int b = sub; b < nblk; b += 4) s += partial[b * 64 + j];
    sd[tid] = s; __syncthreads();
    if (sub == 0) tot[j] = sd[tid] + sd[tid + 1] + sd[tid + 2] + sd[tid + 3];
    __syncthreads();
    if (tid < 32) {
        float mu = tot[tid] * invN;
        float var = tot[32 + tid] * invN - mu * mu;
        float a = gamma[tid] * rsqrtf(var + 1e-5f);
        bn_ac[tid] = a;
        bn_ac[32 + tid] = beta[tid] - a * mu;
    }
}

// ---------- layer B (in-place): t = relu(bn(t)) @ W2 + b2 (+relu) ----------
__global__ __launch_bounds__(256) void layerB32_k(
    float* t_io, const float* __restrict__ bn_ac,
    const float* __restrict__ W2, const float* __restrict__ b2, int Nn)
{
    int tid = threadIdx.x;
    int j = tid & 31, grp = tid >> 5;
    float a = bn_ac[j], c = bn_ac[32 + j];
    float wc[32];
#pragma unroll
    for (int k = 0; k < 32; k++) wc[k] = W2[k * 32 + j];
    float bj = b2[j];
    for (int n = blockIdx.x * 8 + grp; n < Nn; n += gridDim.x * 8) {
        float t = t_io[n * 32 + j];
        float u = fmaxf(fmaf(a, t, c), 0.f);
        float o = bj;
#pragma unroll
        for (int k = 0; k < 32; k++) o = fmaf(__shfl(u, k, 32), wc[k], o);
        t_io[n * 32 + j] = fmaxf(o, 0.f);
    }
}

__global__ __launch_bounds__(256) void layerB64_k(
    const float* __restrict__ tin, const float* __restrict__ bn_ac,
    const float* __restrict__ W2, const float* __restrict__ b2,
    float* __restrict__ hout, int Nn)
{
    int tid = threadIdx.x;
    int j = tid & 31, grp = tid >> 5;
    float a = bn_ac[j], c = bn_ac[32 + j];
    float wlo[32], whi[32];
#pragma unroll
    for (int k = 0; k < 32; k++) { wlo[k] = W2[k * 64 + j]; whi[k] = W2[k * 64 + 32 + j]; }
    float blo = b2[j], bhi = b2[32 + j];
    for (int n = blockIdx.x * 8 + grp; n < Nn; n += gridDim.x * 8) {
        float t = tin[n * 32 + j];
        float u = fmaxf(fmaf(a, t, c), 0.f);
        float olo = blo, ohi = bhi;
#pragma unroll
        for (int k = 0; k < 32; k++) {
            float uk = __shfl(u, k, 32);
            olo = fmaf(uk, wlo[k], olo);
            ohi = fmaf(uk, whi[k], ohi);
        }
        hout[n * 64 + j] = olo;
        hout[n * 64 + 32 + j] = ohi;
    }
}

// ---------- pooling ----------
__global__ void pool1_k(const float* __restrict__ h5, const int* __restrict__ batch,
                        unsigned* __restrict__ maxb, float* __restrict__ sumb, int Nn)
{
    int ch = threadIdx.x & 63, slot = threadIdx.x >> 6;
    int base = blockIdx.x * 256 + slot * 64;
    int g = -1; float mx = 0.f, sm = 0.f;
    for (int i = 0; i < 64; i++) {
        int node = base + i;
        if (node >= Nn) break;
        int gn = batch[node];
        float v = h5[node * 64 + ch];
        if (gn != g) {
            if (g >= 0) { atomicMax(&maxb[g * 64 + ch], encf(mx)); atomicAdd(&sumb[g * 64 + ch], sm); }
            g = gn; mx = v; sm = v;
        } else { mx = fmaxf(mx, v); sm += v; }
    }
    if (g >= 0) { atomicMax(&maxb[g * 64 + ch], encf(mx)); atomicAdd(&sumb[g * 64 + ch], sm); }
}

__global__ void final_k(const unsigned* __restrict__ maxb, const float* __restrict__ sumb,
                        const int* __restrict__ batch, int Nn, float* __restrict__ out)
{
    int g = blockIdx.x, tid = threadIdx.x;
    int a = 0, b = Nn;
    while (a < b) { int m = (a + b) >> 1; if (batch[m] < g) a = m + 1; else b = m; }
    int lo0 = a;
    a = 0; b = Nn;
    while (a < b) { int m = (a + b) >> 1; if (batch[m] < g + 1) a = m + 1; else b = m; }
    int hi0 = a;
    float inv = 1.f / fmaxf((float)(hi0 - lo0), 1.f);
    if (tid < 64) out[g * 128 + tid] = decf(maxb[g * 64 + tid]);
    else          out[g * 128 + tid] = sumb[g * 64 + (tid - 64)] * inv;
}

extern "C" void kernel_launch(void* const* d_in, const int* in_sizes, int n_in,
                              void* d_out, int out_size, void* d_ws, size_t ws_size,
                              hipStream_t stream) {
    const float* x    = (const float*)d_in[0];
    const int*   ei   = (const int*)d_in[1];
    const int*   ety  = (const int*)d_in[2];
    const int*   batch= (const int*)d_in[3];
    const float* emb  = (const float*)d_in[4];
    const float* W1s  = (const float*)d_in[5];
    const float* b1s  = (const float*)d_in[6];
    const float* g1s  = (const float*)d_in[7];
    const float* be1s = (const float*)d_in[8];
    const float* W2s  = (const float*)d_in[9];
    const float* b2s  = (const float*)d_in[10];
    const float* w15  = (const float*)d_in[11];
    const float* b15  = (const float*)d_in[12];
    const float* g5   = (const float*)d_in[13];
    const float* be5  = (const float*)d_in[14];
    const float* w25  = (const float*)d_in[15];
    const float* b25  = (const float*)d_in[16];

    int N = in_sizes[0] / 32;
    int E = in_sizes[1] / 2;
    int G = out_size / 128;

    int sBits = 1; while ((1 << sBits) < N + 1) sBits++;           // fits sentinel s=N
    int shift = 0; while (((N - 1) >> shift) >= 256) shift++;
    int nbUsed = ((N - 1) >> shift) + 1;
    int nblkE = (E + 4095) / 4096;

    char* wsb = (char*)d_ws;
    size_t o = 0;
    size_t hBytes = (size_t)(N + 1) * 32 * 4;
    size_t binBytes = (size_t)E * 4;
    size_t r0 = hBytes > binBytes ? hBytes : binBytes;
    float*    P      = (float*)(wsb + o);
    unsigned* binned = (unsigned*)(wsb + o);   // alias: dead before copyx
    o += r0;
    float*    Q      = (float*)(wsb + o); o += hBytes;
    float*    h5w    = (float*)(wsb + o); o += (size_t)N * 64 * 4;
    int*      rowptr = (int*)(wsb + o);   o += ((size_t)N + 2) * 4;
    unsigned* sorted = (unsigned*)(wsb + o); o += (size_t)E * 4;
    int*      chunkTot = (int*)(wsb + o); o += 1024;
    int*      chunkOff = (int*)(wsb + o); o += 1024;
    float*    partial  = (float*)(wsb + o); o += (size_t)NBLKA * 64 * 4;
    float*    bn_ac    = (float*)(wsb + o); o += 64 * 4;
    unsigned* maxb     = (unsigned*)(wsb + o); o += (size_t)G * 64 * 4;
    float*    sumb     = (float*)(wsb + o); o += (size_t)G * 64 * 4;
    int*      cntMat   = (int*)(wsb + o); o += (size_t)nbUsed * nblkE * 4;

    // ---- CSR build ----
    passA_k<<<nblkE, 256, 0, stream>>>(ei + E, E, cntMat, shift, nblkE, nbUsed);
    int total2 = nbUsed * nblkE;
    int nchunk2 = (total2 + 2047) / 2048;
    scanA_k<<<nchunk2, 256, 0, stream>>>(cntMat, total2, chunkTot);
    scanB_k<<<1, 256, 0, stream>>>(chunkTot, nchunk2, chunkOff);
    scanC2_k<<<nchunk2, 256, 0, stream>>>(cntMat, total2, chunkOff);
    passB_k<<<nblkE, 256, 0, stream>>>(ei, ety, E, cntMat, binned, shift, sBits, nblkE, nbUsed);
    passC_k<<<nbUsed, 256, 0, stream>>>(binned, cntMat, nblkE, rowptr, sorted, N, E, shift, sBits, nbUsed);
    copyx_k<<<(N * 8 + 255) / 256, 256, 0, stream>>>(x, P, Q, N);
    initpool_k<<<(G * 64 + 255) / 256, 256, 0, stream>>>(maxb, sumb, G * 64);

    unsigned sentw = (unsigned)N;   // sentinel edge word: s=N, t=0

    // ---- 5 GINE layers (ping-pong P<->Q, layerB32 in place) ----
    float* inb = P;
    float* outb = Q;
    for (int L = 0; L < 5; ++L) {
        const float* W1 = (L < 4) ? W1s + L * 1024 : w15;
        const float* b1 = (L < 4) ? b1s + L * 32  : b15;
        const float* ga = (L < 4) ? g1s + L * 32  : g5;
        const float* be = (L < 4) ? be1s + L * 32 : be5;
        const float* W2 = (L < 4) ? W2s + L * 1024 : w25;
        const float* b2 = (L < 4) ? b2s + L * 32  : b25;

        layerA_k<<<NBLKA, 256, 0, stream>>>(inb, rowptr, sorted, emb, W1, b1, outb, partial, N, sBits, sentw);
        bnred_k<<<1, 256, 0, stream>>>(partial, NBLKA, ga, be, bn_ac, 1.f / (float)N);
        if (L < 4) {
            layerB32_k<<<1024, 256, 0, stream>>>(outb, bn_ac, W2, b2, N);
            float* tmp = inb; inb = outb; outb = tmp;
        } else {
            layerB64_k<<<1024, 256, 0, stream>>>(outb, bn_ac, W2, b2, h5w, N);
        }
    }

    // ---- pooling ----
    pool1_k<<<(N + 255) / 256, 256, 0, stream>>>(h5w, batch, maxb, sumb, N);
    final_k<<<G, 128, 0, stream>>>(maxb, sumb, batch, N, (float*)d_out);
}

// Round 6
// 767.060 us; speedup vs baseline: 2.7044x; 1.8048x over previous
//
#include <hip/hip_runtime.h>

#define NBLKA 2048

__device__ __forceinline__ unsigned encf(float x) {
    unsigned u = __float_as_uint(x);
    return (u & 0x80000000u) ? ~u : (u | 0x80000000u);
}
__device__ __forceinline__ float decf(unsigned u) {
    u = (u & 0x80000000u) ? (u & 0x7FFFFFFFu) : ~u;
    return __uint_as_float(u);
}

// ============ CSR build: deterministic matrix-scan counting sort ============

__global__ __launch_bounds__(256) void passA_k(const int* __restrict__ dst, int E,
                                               int* __restrict__ cntMat, int shift,
                                               int nblk, int nbUsed) {
    __shared__ int hist[256];
    hist[threadIdx.x] = 0;
    __syncthreads();
    int base = blockIdx.x * 4096;
#pragma unroll
    for (int r = 0; r < 16; r++) {
        int i = base + threadIdx.x + r * 256;
        if (i < E) atomicAdd(&hist[dst[i] >> shift], 1);
    }
    __syncthreads();
    if (threadIdx.x < nbUsed) cntMat[threadIdx.x * nblk + blockIdx.x] = hist[threadIdx.x];
}

__global__ void scanA_k(int* __restrict__ data, int total, int* __restrict__ chunkTot) {
    __shared__ int sd[256];
    int tid = threadIdx.x;
    int base = blockIdx.x * 2048 + tid * 8;
    int v[8]; int s = 0;
#pragma unroll
    for (int r = 0; r < 8; r++) {
        int idx = base + r;
        int x = (idx < total) ? data[idx] : 0;
        s += x; v[r] = s;
    }
    sd[tid] = s; __syncthreads();
    for (int off = 1; off < 256; off <<= 1) {
        int x = (tid >= off) ? sd[tid - off] : 0;
        __syncthreads();
        sd[tid] += x;
        __syncthreads();
    }
    int prev = (tid > 0) ? sd[tid - 1] : 0;
#pragma unroll
    for (int r = 0; r < 8; r++) {
        int idx = base + r;
        if (idx < total) data[idx] = v[r] + prev;
    }
    if (tid == 255) chunkTot[blockIdx.x] = sd[255];
}

__global__ void scanB_k(const int* __restrict__ chunkTot, int nchunk, int* __restrict__ chunkOff) {
    __shared__ int sd[256];
    int tid = threadIdx.x;
    int v = (tid < nchunk) ? chunkTot[tid] : 0;
    sd[tid] = v; __syncthreads();
    for (int off = 1; off < 256; off <<= 1) {
        int x = (tid >= off) ? sd[tid - off] : 0;
        __syncthreads();
        sd[tid] += x;
        __syncthreads();
    }
    if (tid < nchunk) chunkOff[tid] = sd[tid] - v;
}

__global__ void scanC2_k(int* __restrict__ data, int total, const int* __restrict__ chunkOff) {
    int off = chunkOff[blockIdx.x];
    int base = blockIdx.x * 2048 + threadIdx.x * 8;
#pragma unroll
    for (int r = 0; r < 8; r++) {
        int idx = base + r;
        if (idx < total) data[idx] += off;
    }
}

__global__ __launch_bounds__(256) void passB_k(const int* __restrict__ ei,
                                               const int* __restrict__ ety, int E,
                                               const int* __restrict__ cntScan,
                                               unsigned* __restrict__ binned,
                                               int shift, int sBits, int nblk, int nbUsed) {
    __shared__ unsigned stage[4096];
    __shared__ int bkid[4096];
    __shared__ int hist[256], sd[256], cursor[256], rebase[256];
    int tid = threadIdx.x;
    int base = blockIdx.x * 4096;
    hist[tid] = 0;
    __syncthreads();

    unsigned ent[16];
    int bk[16];
    int lowmask = (1 << shift) - 1;
#pragma unroll
    for (int r = 0; r < 16; r++) {
        int i = base + tid + r * 256;
        if (i < E) {
            int s = ei[i];
            int d = ei[E + i];
            int t = ety[i];
            ent[r] = ((unsigned)(d & lowmask) << (sBits + 1)) | ((unsigned)t << sBits) | (unsigned)s;
            bk[r] = d >> shift;
            atomicAdd(&hist[bk[r]], 1);
        } else bk[r] = -1;
    }
    __syncthreads();

    int h = hist[tid];
    sd[tid] = h; __syncthreads();
    for (int off = 1; off < 256; off <<= 1) {
        int x = (tid >= off) ? sd[tid - off] : 0;
        __syncthreads();
        sd[tid] += x;
        __syncthreads();
    }
    int excl = sd[tid] - h;
    cursor[tid] = excl;
    int gb = 0;
    if (tid < nbUsed && h > 0) gb = cntScan[tid * nblk + blockIdx.x] - h;
    rebase[tid] = gb - excl;
    __syncthreads();

#pragma unroll
    for (int r = 0; r < 16; r++) {
        if (bk[r] >= 0) {
            int p = atomicAdd(&cursor[bk[r]], 1);
            stage[p] = ent[r];
            bkid[p] = bk[r];
        }
    }
    __syncthreads();

    int cnt = E - base; if (cnt > 4096) cnt = 4096;
    for (int i = tid; i < cnt; i += 256)
        binned[rebase[bkid[i]] + i] = stage[i];
}

__global__ __launch_bounds__(256) void passC_k(const unsigned* __restrict__ binned,
                                               const int* __restrict__ cntScan,
                                               int nblk, int* __restrict__ rowptr,
                                               unsigned* __restrict__ sorted,
                                               int N, int E, int shift, int sBits,
                                               int nbUsed) {
    __shared__ unsigned stage[12288];
    __shared__ int hist[512], cursor[512], sd[256];
    int tid = threadIdx.x;
    int b = blockIdx.x;
    int s = (b == 0) ? 0 : cntScan[b * nblk - 1];
    int e = cntScan[(b + 1) * nblk - 1];
    int nodeBase = b << shift;
    int half = 1 << (shift - 1);
    int dshift = sBits + 1;
    int segBase = s;

    for (int ph = 0; ph < 2; ph++) {
        int lnBase = ph * half;
        hist[tid] = 0; hist[tid + 256] = 0;
        __syncthreads();
        for (int i = s + tid; i < e; i += 256) {
            int ln = (int)(binned[i] >> dshift) - lnBase;
            if (ln >= 0 && ln < half) atomicAdd(&hist[ln], 1);
        }
        __syncthreads();
        int v0 = hist[2 * tid], v1 = hist[2 * tid + 1];
        int sum2 = v0 + v1;
        sd[tid] = sum2; __syncthreads();
        for (int off = 1; off < 256; off <<= 1) {
            int x = (tid >= off) ? sd[tid - off] : 0;
            __syncthreads();
            sd[tid] += x;
            __syncthreads();
        }
        int exclPair = sd[tid] - sum2;
        int total = sd[255];
        __syncthreads();
        hist[2 * tid] = exclPair;
        hist[2 * tid + 1] = exclPair + v0;
        cursor[2 * tid] = exclPair;
        cursor[2 * tid + 1] = exclPair + v0;
        __syncthreads();
        for (int i = s + tid; i < e; i += 256) {
            unsigned en = binned[i];
            int ln = (int)(en >> dshift) - lnBase;
            if (ln >= 0 && ln < half) {
                int p = atomicAdd(&cursor[ln], 1);
                if (p < 12288) stage[p] = en;
            }
        }
        __syncthreads();
        for (int k = tid; k < total; k += 256)
            if (k < 12288) sorted[segBase + k] = stage[k];
        for (int i = tid; i < half; i += 256) {
            int n = nodeBase + lnBase + i;
            if (n < N) rowptr[n] = segBase + hist[i];
        }
        segBase += total;
        __syncthreads();
    }
    if (b == nbUsed - 1 && tid == 0) rowptr[N] = E;
}

__global__ void initpool_k(unsigned* __restrict__ maxb, float* __restrict__ sumb, int n) {
    int i = blockIdx.x * blockDim.x + threadIdx.x;
    if (i < n) { maxb[i] = 0x007FFFFFu; sumb[i] = 0.f; }
}

// copy x into sentinel-extended buffer P; set sentinel rows of P and Q to -1e30
__global__ void copyx_k(const float* __restrict__ x, float* __restrict__ P,
                        float* __restrict__ Q, int N) {
    int i = blockIdx.x * 256 + threadIdx.x;
    int tot = N * 8;
    if (i < tot) ((float4*)P)[i] = ((const float4*)x)[i];
    if (i < 8) {
        float4 m = {-1e30f, -1e30f, -1e30f, -1e30f};
        ((float4*)P)[tot + i] = m;
        ((float4*)Q)[tot + i] = m;
    }
}

// ---------- layer A: 16 ch-lanes x 2 edge slots per 32-group ----------
__global__ __launch_bounds__(256) void layerA_k(
    const float* __restrict__ hin, const int* __restrict__ rowptr,
    const unsigned* __restrict__ sorted, const float* __restrict__ emb,
    const float* __restrict__ W1, const float* __restrict__ b1,
    float* __restrict__ tout, float* __restrict__ partial, int Nn, int sBits,
    unsigned sentw)
{
    const float2* hin2 = (const float2*)hin;
    float2* tout2 = (float2*)tout;
    int tid = threadIdx.x;
    int gl = tid & 31;          // lane within group
    int c = gl & 15;            // channel-pair index (channels 2c, 2c+1)
    int slot = gl >> 4;         // edge slot 0/1 (also k-half for matmul)
    int grp = tid >> 5;         // group within block (0..7)
    unsigned smask = (1u << sBits) - 1u;

    float2 w1c[16];
#pragma unroll
    for (int kk = 0; kk < 16; kk++)
        w1c[kk] = *(const float2*)&W1[(16 * slot + kk) * 32 + 2 * c];
    float2 b1p = *(const float2*)&b1[2 * c];
    float2 e0p = *(const float2*)&emb[2 * c];
    float2 e1p = *(const float2*)&emb[32 + 2 * c];

    __shared__ float zl[8][32];
    __shared__ float ls[8][32], lq[8][32];

    float2 bsum = {0.f, 0.f}, bsq = {0.f, 0.f};

    int gid0 = (blockIdx.x * 256 + tid) >> 5;
    int nG = (gridDim.x * 256) >> 5;

    for (int n = gid0; n < Nn; n += nG) {
        int es = rowptr[n], ee = rowptr[n + 1];
        float accx = 0.f, accy = 0.f;
        for (int e0 = es; e0 < ee; e0 += 32) {
            int idx = e0 + gl;
            unsigned pv = (idx < ee) ? sorted[idx] : sentw;
#pragma unroll
            for (int kk = 0; kk < 16; kk++) {
                unsigned p = (unsigned)__shfl((int)pv, kk, 16);
                unsigned s = p & smask;
                float2 h = hin2[s * 16u + (unsigned)c];
                bool t1 = ((p >> sBits) & 1u) != 0u;
                float evx = t1 ? e1p.x : e0p.x;
                float evy = t1 ? e1p.y : e0p.y;
                accx += fmaxf(h.x + evx, 0.f);
                accy += fmaxf(h.y + evy, 0.f);
            }
        }
        accx += __shfl_xor(accx, 16);
        accy += __shfl_xor(accy, 16);
        float2 hn = hin2[(unsigned)n * 16u + (unsigned)c];
        accx += hn.x; accy += hn.y;

        if (slot == 0) { zl[grp][2 * c] = accx; zl[grp][2 * c + 1] = accy; }
        float tx = 0.f, ty = 0.f;
#pragma unroll
        for (int kk = 0; kk < 16; kk++) {
            float zk = zl[grp][16 * slot + kk];
            tx = fmaf(zk, w1c[kk].x, tx);
            ty = fmaf(zk, w1c[kk].y, ty);
        }
        tx += __shfl_xor(tx, 16);
        ty += __shfl_xor(ty, 16);
        tx += b1p.x; ty += b1p.y;
        if (slot == 0) { float2 tp; tp.x = tx; tp.y = ty; tout2[(unsigned)n * 16u + (unsigned)c] = tp; }
        bsum.x += tx; bsum.y += ty;
        bsq.x = fmaf(tx, tx, bsq.x);
        bsq.y = fmaf(ty, ty, bsq.y);
    }

    if (slot == 0) {
        ls[grp][2 * c] = bsum.x; ls[grp][2 * c + 1] = bsum.y;
        lq[grp][2 * c] = bsq.x;  lq[grp][2 * c + 1] = bsq.y;
    }
    __syncthreads();
    if (tid < 32) {
        float s = 0.f, q = 0.f;
#pragma unroll
        for (int r = 0; r < 8; r++) { s += ls[r][tid]; q += lq[r][tid]; }
        partial[blockIdx.x * 64 + tid] = s;
        partial[blockIdx.x * 64 + 32 + tid] = q;
    }
}

// ---------- BN stat reduce, two-stage parallel ----------
// stage 1: 64 blocks, each reduces 32 partial rows -> partial2[block][64]
__global__ __launch_bounds__(256) void bnred1_k(const float* __restrict__ partial,
                                                float* __restrict__ partial2) {
    __shared__ float sd[4][64];
    int tid = threadIdx.x;
    int c = tid & 63, q = tid >> 6;          // 4 quarters x 8 rows
    int rowBase = blockIdx.x * 32 + q * 8;
    float s = 0.f;
#pragma unroll
    for (int r = 0; r < 8; r++) s += partial[(rowBase + r) * 64 + c];
    sd[q][c] = s;
    __syncthreads();
    if (q == 0) partial2[blockIdx.x * 64 + c] = sd[0][c] + sd[1][c] + sd[2][c] + sd[3][c];
}

// stage 2: 1 block reduces partial2[64][64] -> bn_ac
__global__ __launch_bounds__(256) void bnred2_k(const float* __restrict__ partial2,
                                                const float* __restrict__ gamma,
                                                const float* __restrict__ beta,
                                                float* __restrict__ bn_ac, float invN) {
    __shared__ float sd[4][64];
    int tid = threadIdx.x;
    int c = tid & 63, q = tid >> 6;          // 4 quarters x 16 rows
    float s = 0.f;
#pragma unroll
    for (int r = 0; r < 16; r++) s += partial2[(q * 16 + r) * 64 + c];
    sd[q][c] = s;
    __syncthreads();
    if (tid < 32) {
        float mu  = (sd[0][tid] + sd[1][tid] + sd[2][tid] + sd[3][tid]) * invN;
        float sq  = (sd[0][tid + 32] + sd[1][tid + 32] + sd[2][tid + 32] + sd[3][tid + 32]) * invN;
        float var = sq - mu * mu;
        float a = gamma[tid] * rsqrtf(var + 1e-5f);
        bn_ac[tid] = a;
        bn_ac[32 + tid] = beta[tid] - a * mu;
    }
}

// ---------- layer B (in-place): t = relu(bn(t)) @ W2 + b2 (+relu) ----------
__global__ __launch_bounds__(256) void layerB32_k(
    float* t_io, const float* __restrict__ bn_ac,
    const float* __restrict__ W2, const float* __restrict__ b2, int Nn)
{
    int tid = threadIdx.x;
    int j = tid & 31, grp = tid >> 5;
    float a = bn_ac[j], c = bn_ac[32 + j];
    float wc[32];
#pragma unroll
    for (int k = 0; k < 32; k++) wc[k] = W2[k * 32 + j];
    float bj = b2[j];
    for (int n = blockIdx.x * 8 + grp; n < Nn; n += gridDim.x * 8) {
        float t = t_io[n * 32 + j];
        float u = fmaxf(fmaf(a, t, c), 0.f);
        float o = bj;
#pragma unroll
        for (int k = 0; k < 32; k++) o = fmaf(__shfl(u, k, 32), wc[k], o);
        t_io[n * 32 + j] = fmaxf(o, 0.f);
    }
}

__global__ __launch_bounds__(256) void layerB64_k(
    const float* __restrict__ tin, const float* __restrict__ bn_ac,
    const float* __restrict__ W2, const float* __restrict__ b2,
    float* __restrict__ hout, int Nn)
{
    int tid = threadIdx.x;
    int j = tid & 31, grp = tid >> 5;
    float a = bn_ac[j], c = bn_ac[32 + j];
    float wlo[32], whi[32];
#pragma unroll
    for (int k = 0; k < 32; k++) { wlo[k] = W2[k * 64 + j]; whi[k] = W2[k * 64 + 32 + j]; }
    float blo = b2[j], bhi = b2[32 + j];
    for (int n = blockIdx.x * 8 + grp; n < Nn; n += gridDim.x * 8) {
        float t = tin[n * 32 + j];
        float u = fmaxf(fmaf(a, t, c), 0.f);
        float olo = blo, ohi = bhi;
#pragma unroll
        for (int k = 0; k < 32; k++) {
            float uk = __shfl(u, k, 32);
            olo = fmaf(uk, wlo[k], olo);
            ohi = fmaf(uk, whi[k], ohi);
        }
        hout[n * 64 + j] = olo;
        hout[n * 64 + 32 + j] = ohi;
    }
}

// ---------- pooling ----------
__global__ void pool1_k(const float* __restrict__ h5, const int* __restrict__ batch,
                        unsigned* __restrict__ maxb, float* __restrict__ sumb, int Nn)
{
    int ch = threadIdx.x & 63, slot = threadIdx.x >> 6;
    int base = blockIdx.x * 256 + slot * 64;
    int g = -1; float mx = 0.f, sm = 0.f;
    for (int i = 0; i < 64; i++) {
        int node = base + i;
        if (node >= Nn) break;
        int gn = batch[node];
        float v = h5[node * 64 + ch];
        if (gn != g) {
            if (g >= 0) { atomicMax(&maxb[g * 64 + ch], encf(mx)); atomicAdd(&sumb[g * 64 + ch], sm); }
            g = gn; mx = v; sm = v;
        } else { mx = fmaxf(mx, v); sm += v; }
    }
    if (g >= 0) { atomicMax(&maxb[g * 64 + ch], encf(mx)); atomicAdd(&sumb[g * 64 + ch], sm); }
}

__global__ void final_k(const unsigned* __restrict__ maxb, const float* __restrict__ sumb,
                        const int* __restrict__ batch, int Nn, float* __restrict__ out)
{
    int g = blockIdx.x, tid = threadIdx.x;
    int a = 0, b = Nn;
    while (a < b) { int m = (a + b) >> 1; if (batch[m] < g) a = m + 1; else b = m; }
    int lo0 = a;
    a = 0; b = Nn;
    while (a < b) { int m = (a + b) >> 1; if (batch[m] < g + 1) a = m + 1; else b = m; }
    int hi0 = a;
    float inv = 1.f / fmaxf((float)(hi0 - lo0), 1.f);
    if (tid < 64) out[g * 128 + tid] = decf(maxb[g * 64 + tid]);
    else          out[g * 128 + tid] = sumb[g * 64 + (tid - 64)] * inv;
}

extern "C" void kernel_launch(void* const* d_in, const int* in_sizes, int n_in,
                              void* d_out, int out_size, void* d_ws, size_t ws_size,
                              hipStream_t stream) {
    const float* x    = (const float*)d_in[0];
    const int*   ei   = (const int*)d_in[1];
    const int*   ety  = (const int*)d_in[2];
    const int*   batch= (const int*)d_in[3];
    const float* emb  = (const float*)d_in[4];
    const float* W1s  = (const float*)d_in[5];
    const float* b1s  = (const float*)d_in[6];
    const float* g1s  = (const float*)d_in[7];
    const float* be1s = (const float*)d_in[8];
    const float* W2s  = (const float*)d_in[9];
    const float* b2s  = (const float*)d_in[10];
    const float* w15  = (const float*)d_in[11];
    const float* b15  = (const float*)d_in[12];
    const float* g5   = (const float*)d_in[13];
    const float* be5  = (const float*)d_in[14];
    const float* w25  = (const float*)d_in[15];
    const float* b25  = (const float*)d_in[16];

    int N = in_sizes[0] / 32;
    int E = in_sizes[1] / 2;
    int G = out_size / 128;

    int sBits = 1; while ((1 << sBits) < N + 1) sBits++;
    int shift = 0; while (((N - 1) >> shift) >= 256) shift++;
    int nbUsed = ((N - 1) >> shift) + 1;
    int nblkE = (E + 4095) / 4096;

    char* wsb = (char*)d_ws;
    size_t o = 0;
    size_t hBytes = (size_t)(N + 1) * 32 * 4;
    size_t binBytes = (size_t)E * 4;
    size_t r0 = hBytes > binBytes ? hBytes : binBytes;
    float*    P      = (float*)(wsb + o);
    unsigned* binned = (unsigned*)(wsb + o);
    o += r0;
    float*    Q      = (float*)(wsb + o); o += hBytes;
    float*    h5w    = (float*)(wsb + o); o += (size_t)N * 64 * 4;
    int*      rowptr = (int*)(wsb + o);   o += ((size_t)N + 2) * 4;
    unsigned* sorted = (unsigned*)(wsb + o); o += (size_t)E * 4;
    int*      chunkTot = (int*)(wsb + o); o += 1024;
    int*      chunkOff = (int*)(wsb + o); o += 1024;
    float*    partial  = (float*)(wsb + o); o += (size_t)NBLKA * 64 * 4;
    float*    partial2 = (float*)(wsb + o); o += 64 * 64 * 4;
    float*    bn_ac    = (float*)(wsb + o); o += 64 * 4;
    unsigned* maxb     = (unsigned*)(wsb + o); o += (size_t)G * 64 * 4;
    float*    sumb     = (float*)(wsb + o); o += (size_t)G * 64 * 4;
    int*      cntMat   = (int*)(wsb + o); o += (size_t)nbUsed * nblkE * 4;

    // ---- CSR build ----
    passA_k<<<nblkE, 256, 0, stream>>>(ei + E, E, cntMat, shift, nblkE, nbUsed);
    int total2 = nbUsed * nblkE;
    int nchunk2 = (total2 + 2047) / 2048;
    scanA_k<<<nchunk2, 256, 0, stream>>>(cntMat, total2, chunkTot);
    scanB_k<<<1, 256, 0, stream>>>(chunkTot, nchunk2, chunkOff);
    scanC2_k<<<nchunk2, 256, 0, stream>>>(cntMat, total2, chunkOff);
    passB_k<<<nblkE, 256, 0, stream>>>(ei, ety, E, cntMat, binned, shift, sBits, nblkE, nbUsed);
    passC_k<<<nbUsed, 256, 0, stream>>>(binned, cntMat, nblkE, rowptr, sorted, N, E, shift, sBits, nbUsed);
    copyx_k<<<(N * 8 + 255) / 256, 256, 0, stream>>>(x, P, Q, N);
    initpool_k<<<(G * 64 + 255) / 256, 256, 0, stream>>>(maxb, sumb, G * 64);

    unsigned sentw = (unsigned)N;

    // ---- 5 GINE layers (ping-pong P<->Q, layerB32 in place) ----
    float* inb = P;
    float* outb = Q;
    for (int L = 0; L < 5; ++L) {
        const float* W1 = (L < 4) ? W1s + L * 1024 : w15;
        const float* b1 = (L < 4) ? b1s + L * 32  : b15;
        const float* ga = (L < 4) ? g1s + L * 32  : g5;
        const float* be = (L < 4) ? be1s + L * 32 : be5;
        const float* W2 = (L < 4) ? W2s + L * 1024 : w25;
        const float* b2 = (L < 4) ? b2s + L * 32  : b25;

        layerA_k<<<NBLKA, 256, 0, stream>>>(inb, rowptr, sorted, emb, W1, b1, outb, partial, N, sBits, sentw);
        bnred1_k<<<64, 256, 0, stream>>>(partial, partial2);
        bnred2_k<<<1, 256, 0, stream>>>(partial2, ga, be, bn_ac, 1.f / (float)N);
        if (L < 4) {
            layerB32_k<<<1024, 256, 0, stream>>>(outb, bn_ac, W2, b2, N);
            float* tmp = inb; inb = outb; outb = tmp;
        } else {
            layerB64_k<<<1024, 256, 0, stream>>>(outb, bn_ac, W2, b2, h5w, N);
        }
    }

    // ---- pooling ----
    pool1_k<<<(N + 255) / 256, 256, 0, stream>>>(h5w, batch, maxb, sumb, N);
    final_k<<<G, 128, 0, stream>>>(maxb, sumb, batch, N, (float*)d_out);
}

// Round 7
// 734.776 us; speedup vs baseline: 2.8232x; 1.0439x over previous
//
#include <hip/hip_runtime.h>

#define NBLKA 2048

__device__ __forceinline__ unsigned encf(float x) {
    unsigned u = __float_as_uint(x);
    return (u & 0x80000000u) ? ~u : (u | 0x80000000u);
}
__device__ __forceinline__ float decf(unsigned u) {
    u = (u & 0x80000000u) ? (u & 0x7FFFFFFFu) : ~u;
    return __uint_as_float(u);
}
__device__ __forceinline__ unsigned bf16rne(float f) {
    unsigned u = __float_as_uint(f);
    return (u + 0x7FFFu + ((u >> 16) & 1u)) >> 16;
}

// ============ CSR build: deterministic matrix-scan counting sort ============

__global__ __launch_bounds__(256) void passA_k(const int* __restrict__ dst, int E,
                                               int* __restrict__ cntMat, int shift,
                                               int nblk, int nbUsed) {
    __shared__ int hist[256];
    hist[threadIdx.x] = 0;
    __syncthreads();
    int base = blockIdx.x * 4096;
#pragma unroll
    for (int r = 0; r < 16; r++) {
        int i = base + threadIdx.x + r * 256;
        if (i < E) atomicAdd(&hist[dst[i] >> shift], 1);
    }
    __syncthreads();
    if (threadIdx.x < nbUsed) cntMat[threadIdx.x * nblk + blockIdx.x] = hist[threadIdx.x];
}

__global__ void scanA_k(int* __restrict__ data, int total, int* __restrict__ chunkTot) {
    __shared__ int sd[256];
    int tid = threadIdx.x;
    int base = blockIdx.x * 2048 + tid * 8;
    int v[8]; int s = 0;
#pragma unroll
    for (int r = 0; r < 8; r++) {
        int idx = base + r;
        int x = (idx < total) ? data[idx] : 0;
        s += x; v[r] = s;
    }
    sd[tid] = s; __syncthreads();
    for (int off = 1; off < 256; off <<= 1) {
        int x = (tid >= off) ? sd[tid - off] : 0;
        __syncthreads();
        sd[tid] += x;
        __syncthreads();
    }
    int prev = (tid > 0) ? sd[tid - 1] : 0;
#pragma unroll
    for (int r = 0; r < 8; r++) {
        int idx = base + r;
        if (idx < total) data[idx] = v[r] + prev;
    }
    if (tid == 255) chunkTot[blockIdx.x] = sd[255];
}

__global__ void scanB_k(const int* __restrict__ chunkTot, int nchunk, int* __restrict__ chunkOff) {
    __shared__ int sd[256];
    int tid = threadIdx.x;
    int v = (tid < nchunk) ? chunkTot[tid] : 0;
    sd[tid] = v; __syncthreads();
    for (int off = 1; off < 256; off <<= 1) {
        int x = (tid >= off) ? sd[tid - off] : 0;
        __syncthreads();
        sd[tid] += x;
        __syncthreads();
    }
    if (tid < nchunk) chunkOff[tid] = sd[tid] - v;
}

__global__ void scanC2_k(int* __restrict__ data, int total, const int* __restrict__ chunkOff) {
    int off = chunkOff[blockIdx.x];
    int base = blockIdx.x * 2048 + threadIdx.x * 8;
#pragma unroll
    for (int r = 0; r < 8; r++) {
        int idx = base + r;
        if (idx < total) data[idx] += off;
    }
}

__global__ __launch_bounds__(256) void passB_k(const int* __restrict__ ei,
                                               const int* __restrict__ ety, int E,
                                               const int* __restrict__ cntScan,
                                               unsigned* __restrict__ binned,
                                               int shift, int sBits, int nblk, int nbUsed) {
    __shared__ unsigned stage[4096];
    __shared__ int bkid[4096];
    __shared__ int hist[256], sd[256], cursor[256], rebase[256];
    int tid = threadIdx.x;
    int base = blockIdx.x * 4096;
    hist[tid] = 0;
    __syncthreads();

    unsigned ent[16];
    int bk[16];
    int lowmask = (1 << shift) - 1;
#pragma unroll
    for (int r = 0; r < 16; r++) {
        int i = base + tid + r * 256;
        if (i < E) {
            int s = ei[i];
            int d = ei[E + i];
            int t = ety[i];
            ent[r] = ((unsigned)(d & lowmask) << (sBits + 1)) | ((unsigned)t << sBits) | (unsigned)s;
            bk[r] = d >> shift;
            atomicAdd(&hist[bk[r]], 1);
        } else bk[r] = -1;
    }
    __syncthreads();

    int h = hist[tid];
    sd[tid] = h; __syncthreads();
    for (int off = 1; off < 256; off <<= 1) {
        int x = (tid >= off) ? sd[tid - off] : 0;
        __syncthreads();
        sd[tid] += x;
        __syncthreads();
    }
    int excl = sd[tid] - h;
    cursor[tid] = excl;
    int gb = 0;
    if (tid < nbUsed && h > 0) gb = cntScan[tid * nblk + blockIdx.x] - h;
    rebase[tid] = gb - excl;
    __syncthreads();

#pragma unroll
    for (int r = 0; r < 16; r++) {
        if (bk[r] >= 0) {
            int p = atomicAdd(&cursor[bk[r]], 1);
            stage[p] = ent[r];
            bkid[p] = bk[r];
        }
    }
    __syncthreads();

    int cnt = E - base; if (cnt > 4096) cnt = 4096;
    for (int i = tid; i < cnt; i += 256)
        binned[rebase[bkid[i]] + i] = stage[i];
}

__global__ __launch_bounds__(256) void passC_k(const unsigned* __restrict__ binned,
                                               const int* __restrict__ cntScan,
                                               int nblk, int* __restrict__ rowptr,
                                               unsigned* __restrict__ sorted,
                                               int N, int E, int shift, int sBits,
                                               int nbUsed) {
    __shared__ unsigned stage[12288];
    __shared__ int hist[512], cursor[512], sd[256];
    int tid = threadIdx.x;
    int b = blockIdx.x;
    int s = (b == 0) ? 0 : cntScan[b * nblk - 1];
    int e = cntScan[(b + 1) * nblk - 1];
    int nodeBase = b << shift;
    int half = 1 << (shift - 1);
    int dshift = sBits + 1;
    int segBase = s;

    for (int ph = 0; ph < 2; ph++) {
        int lnBase = ph * half;
        hist[tid] = 0; hist[tid + 256] = 0;
        __syncthreads();
        for (int i = s + tid; i < e; i += 256) {
            int ln = (int)(binned[i] >> dshift) - lnBase;
            if (ln >= 0 && ln < half) atomicAdd(&hist[ln], 1);
        }
        __syncthreads();
        int v0 = hist[2 * tid], v1 = hist[2 * tid + 1];
        int sum2 = v0 + v1;
        sd[tid] = sum2; __syncthreads();
        for (int off = 1; off < 256; off <<= 1) {
            int x = (tid >= off) ? sd[tid - off] : 0;
            __syncthreads();
            sd[tid] += x;
            __syncthreads();
        }
        int exclPair = sd[tid] - sum2;
        int total = sd[255];
        __syncthreads();
        hist[2 * tid] = exclPair;
        hist[2 * tid + 1] = exclPair + v0;
        cursor[2 * tid] = exclPair;
        cursor[2 * tid + 1] = exclPair + v0;
        __syncthreads();
        for (int i = s + tid; i < e; i += 256) {
            unsigned en = binned[i];
            int ln = (int)(en >> dshift) - lnBase;
            if (ln >= 0 && ln < half) {
                int p = atomicAdd(&cursor[ln], 1);
                if (p < 12288) stage[p] = en;
            }
        }
        __syncthreads();
        for (int k = tid; k < total; k += 256)
            if (k < 12288) sorted[segBase + k] = stage[k];
        for (int i = tid; i < half; i += 256) {
            int n = nodeBase + lnBase + i;
            if (n < N) rowptr[n] = segBase + hist[i];
        }
        segBase += total;
        __syncthreads();
    }
    if (b == nbUsed - 1 && tid == 0) rowptr[N] = E;
}

__global__ void initpool_k(unsigned* __restrict__ maxb, float* __restrict__ sumb, int n) {
    int i = blockIdx.x * blockDim.x + threadIdx.x;
    if (i < n) { maxb[i] = 0x007FFFFFu; sumb[i] = 0.f; }
}

// copy x -> packed bf16 pairs in P; set sentinel rows of P and Q
__global__ void copyx_k(const float* __restrict__ x, unsigned* __restrict__ P,
                        unsigned* __restrict__ Q, int N) {
    int i = blockIdx.x * 256 + threadIdx.x;
    int tot = N * 16;
    if (i < tot) {
        float2 v = ((const float2*)x)[i];
        P[i] = bf16rne(v.x) | (bf16rne(v.y) << 16);
    }
    if (i < 16) {
        unsigned sp = bf16rne(-1e30f) | (bf16rne(-1e30f) << 16);
        P[tot + i] = sp;
        Q[tot + i] = sp;
    }
}

// ---------- layer A: 16 ch-lanes x 2 edge slots per 32-group, bf16 h ----------
__global__ __launch_bounds__(256) void layerA_k(
    const unsigned* __restrict__ hin, const int* __restrict__ rowptr,
    const unsigned* __restrict__ sorted, const float* __restrict__ emb,
    const float* __restrict__ W1, const float* __restrict__ b1,
    float* __restrict__ tout, float* __restrict__ partial, int Nn, int sBits,
    unsigned sentw)
{
    float2* tout2 = (float2*)tout;
    int tid = threadIdx.x;
    int gl = tid & 31;
    int c = gl & 15;            // channel-pair index
    int slot = gl >> 4;         // edge slot / k-half
    int grp = tid >> 5;
    unsigned smask = (1u << sBits) - 1u;

    float2 w1c[16];
#pragma unroll
    for (int kk = 0; kk < 16; kk++)
        w1c[kk] = *(const float2*)&W1[(16 * slot + kk) * 32 + 2 * c];
    float2 b1p = *(const float2*)&b1[2 * c];
    float2 e0p = *(const float2*)&emb[2 * c];
    float2 e1p = *(const float2*)&emb[32 + 2 * c];

    __shared__ float zl[8][32];
    __shared__ float ls[8][32], lq[8][32];

    float2 bsum = {0.f, 0.f}, bsq = {0.f, 0.f};

    int gid0 = (blockIdx.x * 256 + tid) >> 5;
    int nG = (gridDim.x * 256) >> 5;

    for (int n = gid0; n < Nn; n += nG) {
        int es = rowptr[n], ee = rowptr[n + 1];
        float accx = 0.f, accy = 0.f;
        for (int e0 = es; e0 < ee; e0 += 32) {
            int idx = e0 + gl;
            unsigned pv = (idx < ee) ? sorted[idx] : sentw;
#pragma unroll
            for (int kk = 0; kk < 16; kk++) {
                unsigned p = (unsigned)__shfl((int)pv, kk, 16);
                unsigned s = p & smask;
                unsigned w = hin[s * 16u + (unsigned)c];
                float hx = __uint_as_float(w << 16);
                float hy = __uint_as_float(w & 0xFFFF0000u);
                bool t1 = ((p >> sBits) & 1u) != 0u;
                float evx = t1 ? e1p.x : e0p.x;
                float evy = t1 ? e1p.y : e0p.y;
                accx += fmaxf(hx + evx, 0.f);
                accy += fmaxf(hy + evy, 0.f);
            }
        }
        accx += __shfl_xor(accx, 16);
        accy += __shfl_xor(accy, 16);
        unsigned wn = hin[(unsigned)n * 16u + (unsigned)c];
        accx += __uint_as_float(wn << 16);
        accy += __uint_as_float(wn & 0xFFFF0000u);

        if (slot == 0) { zl[grp][2 * c] = accx; zl[grp][2 * c + 1] = accy; }
        float tx = 0.f, ty = 0.f;
#pragma unroll
        for (int kk = 0; kk < 16; kk++) {
            float zk = zl[grp][16 * slot + kk];
            tx = fmaf(zk, w1c[kk].x, tx);
            ty = fmaf(zk, w1c[kk].y, ty);
        }
        tx += __shfl_xor(tx, 16);
        ty += __shfl_xor(ty, 16);
        tx += b1p.x; ty += b1p.y;
        if (slot == 0) { float2 tp; tp.x = tx; tp.y = ty; tout2[(unsigned)n * 16u + (unsigned)c] = tp; }
        bsum.x += tx; bsum.y += ty;
        bsq.x = fmaf(tx, tx, bsq.x);
        bsq.y = fmaf(ty, ty, bsq.y);
    }

    if (slot == 0) {
        ls[grp][2 * c] = bsum.x; ls[grp][2 * c + 1] = bsum.y;
        lq[grp][2 * c] = bsq.x;  lq[grp][2 * c + 1] = bsq.y;
    }
    __syncthreads();
    if (tid < 32) {
        float s = 0.f, q = 0.f;
#pragma unroll
        for (int r = 0; r < 8; r++) { s += ls[r][tid]; q += lq[r][tid]; }
        partial[blockIdx.x * 64 + tid] = s;
        partial[blockIdx.x * 64 + 32 + tid] = q;
    }
}

// ---------- BN stat reduce, two-stage parallel ----------
__global__ __launch_bounds__(256) void bnred1_k(const float* __restrict__ partial,
                                                float* __restrict__ partial2) {
    __shared__ float sd[4][64];
    int tid = threadIdx.x;
    int c = tid & 63, q = tid >> 6;
    int rowBase = blockIdx.x * 32 + q * 8;
    float s = 0.f;
#pragma unroll
    for (int r = 0; r < 8; r++) s += partial[(rowBase + r) * 64 + c];
    sd[q][c] = s;
    __syncthreads();
    if (q == 0) partial2[blockIdx.x * 64 + c] = sd[0][c] + sd[1][c] + sd[2][c] + sd[3][c];
}

__global__ __launch_bounds__(256) void bnred2_k(const float* __restrict__ partial2,
                                                const float* __restrict__ gamma,
                                                const float* __restrict__ beta,
                                                float* __restrict__ bn_ac, float invN) {
    __shared__ float sd[4][64];
    int tid = threadIdx.x;
    int c = tid & 63, q = tid >> 6;
    float s = 0.f;
#pragma unroll
    for (int r = 0; r < 16; r++) s += partial2[(q * 16 + r) * 64 + c];
    sd[q][c] = s;
    __syncthreads();
    if (tid < 32) {
        float mu  = (sd[0][tid] + sd[1][tid] + sd[2][tid] + sd[3][tid]) * invN;
        float sq  = (sd[0][tid + 32] + sd[1][tid + 32] + sd[2][tid + 32] + sd[3][tid + 32]) * invN;
        float var = sq - mu * mu;
        float a = gamma[tid] * rsqrtf(var + 1e-5f);
        bn_ac[tid] = a;
        bn_ac[32 + tid] = beta[tid] - a * mu;
    }
}

// ---------- layer B: relu(bn(t)) @ W2 + b2, +relu, write packed bf16 ----------
__global__ __launch_bounds__(256) void layerB32_k(
    const float* __restrict__ tin, const float* __restrict__ bn_ac,
    const float* __restrict__ W2, const float* __restrict__ b2,
    unsigned* __restrict__ hout, int Nn)
{
    int tid = threadIdx.x;
    int j = tid & 31, grp = tid >> 5;
    float a = bn_ac[j], c = bn_ac[32 + j];
    float wc[32];
#pragma unroll
    for (int k = 0; k < 32; k++) wc[k] = W2[k * 32 + j];
    float bj = b2[j];
    for (int n = blockIdx.x * 8 + grp; n < Nn; n += gridDim.x * 8) {
        float t = tin[n * 32 + j];
        float u = fmaxf(fmaf(a, t, c), 0.f);
        float o = bj;
#pragma unroll
        for (int k = 0; k < 32; k++) o = fmaf(__shfl(u, k, 32), wc[k], o);
        unsigned b = bf16rne(fmaxf(o, 0.f));
        unsigned nb = (unsigned)__shfl_xor((int)b, 1, 32);
        if ((j & 1) == 0) hout[(unsigned)n * 16u + (unsigned)(j >> 1)] = b | (nb << 16);
    }
}

__global__ __launch_bounds__(256) void layerB64_k(
    const float* __restrict__ tin, const float* __restrict__ bn_ac,
    const float* __restrict__ W2, const float* __restrict__ b2,
    float* __restrict__ hout, int Nn)
{
    int tid = threadIdx.x;
    int j = tid & 31, grp = tid >> 5;
    float a = bn_ac[j], c = bn_ac[32 + j];
    float wlo[32], whi[32];
#pragma unroll
    for (int k = 0; k < 32; k++) { wlo[k] = W2[k * 64 + j]; whi[k] = W2[k * 64 + 32 + j]; }
    float blo = b2[j], bhi = b2[32 + j];
    for (int n = blockIdx.x * 8 + grp; n < Nn; n += gridDim.x * 8) {
        float t = tin[n * 32 + j];
        float u = fmaxf(fmaf(a, t, c), 0.f);
        float olo = blo, ohi = bhi;
#pragma unroll
        for (int k = 0; k < 32; k++) {
            float uk = __shfl(u, k, 32);
            olo = fmaf(uk, wlo[k], olo);
            ohi = fmaf(uk, whi[k], ohi);
        }
        hout[n * 64 + j] = olo;
        hout[n * 64 + 32 + j] = ohi;
    }
}

// ---------- pooling ----------
__global__ void pool1_k(const float* __restrict__ h5, const int* __restrict__ batch,
                        unsigned* __restrict__ maxb, float* __restrict__ sumb, int Nn)
{
    int ch = threadIdx.x & 63, slot = threadIdx.x >> 6;
    int base = blockIdx.x * 256 + slot * 64;
    int g = -1; float mx = 0.f, sm = 0.f;
    for (int i = 0; i < 64; i++) {
        int node = base + i;
        if (node >= Nn) break;
        int gn = batch[node];
        float v = h5[node * 64 + ch];
        if (gn != g) {
            if (g >= 0) { atomicMax(&maxb[g * 64 + ch], encf(mx)); atomicAdd(&sumb[g * 64 + ch], sm); }
            g = gn; mx = v; sm = v;
        } else { mx = fmaxf(mx, v); sm += v; }
    }
    if (g >= 0) { atomicMax(&maxb[g * 64 + ch], encf(mx)); atomicAdd(&sumb[g * 64 + ch], sm); }
}

__global__ void final_k(const unsigned* __restrict__ maxb, const float* __restrict__ sumb,
                        const int* __restrict__ batch, int Nn, float* __restrict__ out)
{
    int g = blockIdx.x, tid = threadIdx.x;
    int a = 0, b = Nn;
    while (a < b) { int m = (a + b) >> 1; if (batch[m] < g) a = m + 1; else b = m; }
    int lo0 = a;
    a = 0; b = Nn;
    while (a < b) { int m = (a + b) >> 1; if (batch[m] < g + 1) a = m + 1; else b = m; }
    int hi0 = a;
    float inv = 1.f / fmaxf((float)(hi0 - lo0), 1.f);
    if (tid < 64) out[g * 128 + tid] = decf(maxb[g * 64 + tid]);
    else          out[g * 128 + tid] = sumb[g * 64 + (tid - 64)] * inv;
}

extern "C" void kernel_launch(void* const* d_in, const int* in_sizes, int n_in,
                              void* d_out, int out_size, void* d_ws, size_t ws_size,
                              hipStream_t stream) {
    const float* x    = (const float*)d_in[0];
    const int*   ei   = (const int*)d_in[1];
    const int*   ety  = (const int*)d_in[2];
    const int*   batch= (const int*)d_in[3];
    const float* emb  = (const float*)d_in[4];
    const float* W1s  = (const float*)d_in[5];
    const float* b1s  = (const float*)d_in[6];
    const float* g1s  = (const float*)d_in[7];
    const float* be1s = (const float*)d_in[8];
    const float* W2s  = (const float*)d_in[9];
    const float* b2s  = (const float*)d_in[10];
    const float* w15  = (const float*)d_in[11];
    const float* b15  = (const float*)d_in[12];
    const float* g5   = (const float*)d_in[13];
    const float* be5  = (const float*)d_in[14];
    const float* w25  = (const float*)d_in[15];
    const float* b25  = (const float*)d_in[16];

    int N = in_sizes[0] / 32;
    int E = in_sizes[1] / 2;
    int G = out_size / 128;

    int sBits = 1; while ((1 << sBits) < N + 1) sBits++;
    int shift = 0; while (((N - 1) >> shift) >= 256) shift++;
    int nbUsed = ((N - 1) >> shift) + 1;
    int nblkE = (E + 4095) / 4096;

    char* wsb = (char*)d_ws;
    size_t o = 0;
    size_t hPkBytes = (size_t)(N + 1) * 16 * 4;     // packed bf16 pairs
    size_t tbBytes = (size_t)N * 32 * 4;            // f32 t buffer
    size_t binBytes = (size_t)E * 4;
    size_t rtb = tbBytes > binBytes ? tbBytes : binBytes;
    unsigned* P      = (unsigned*)(wsb + o); o += hPkBytes;
    unsigned* Q      = (unsigned*)(wsb + o); o += hPkBytes;
    float*    tb     = (float*)(wsb + o);
    unsigned* binned = (unsigned*)(wsb + o);        // alias: dead before layerA L0
    o += rtb;
    float*    h5w    = (float*)(wsb + o); o += (size_t)N * 64 * 4;
    int*      rowptr = (int*)(wsb + o);   o += ((size_t)N + 2) * 4;
    unsigned* sorted = (unsigned*)(wsb + o); o += (size_t)E * 4;
    int*      chunkTot = (int*)(wsb + o); o += 1024;
    int*      chunkOff = (int*)(wsb + o); o += 1024;
    float*    partial  = (float*)(wsb + o); o += (size_t)NBLKA * 64 * 4;
    float*    partial2 = (float*)(wsb + o); o += 64 * 64 * 4;
    float*    bn_ac    = (float*)(wsb + o); o += 64 * 4;
    unsigned* maxb     = (unsigned*)(wsb + o); o += (size_t)G * 64 * 4;
    float*    sumb     = (float*)(wsb + o); o += (size_t)G * 64 * 4;
    int*      cntMat   = (int*)(wsb + o); o += (size_t)nbUsed * nblkE * 4;

    // ---- CSR build ----
    passA_k<<<nblkE, 256, 0, stream>>>(ei + E, E, cntMat, shift, nblkE, nbUsed);
    int total2 = nbUsed * nblkE;
    int nchunk2 = (total2 + 2047) / 2048;
    scanA_k<<<nchunk2, 256, 0, stream>>>(cntMat, total2, chunkTot);
    scanB_k<<<1, 256, 0, stream>>>(chunkTot, nchunk2, chunkOff);
    scanC2_k<<<nchunk2, 256, 0, stream>>>(cntMat, total2, chunkOff);
    passB_k<<<nblkE, 256, 0, stream>>>(ei, ety, E, cntMat, binned, shift, sBits, nblkE, nbUsed);
    passC_k<<<nbUsed, 256, 0, stream>>>(binned, cntMat, nblkE, rowptr, sorted, N, E, shift, sBits, nbUsed);
    copyx_k<<<(N * 16 + 255) / 256, 256, 0, stream>>>(x, P, Q, N);
    initpool_k<<<(G * 64 + 255) / 256, 256, 0, stream>>>(maxb, sumb, G * 64);

    unsigned sentw = (unsigned)N;

    // ---- 5 GINE layers (ping-pong P<->Q, t via f32 tb) ----
    unsigned* inb = P;
    unsigned* outb = Q;
    for (int L = 0; L < 5; ++L) {
        const float* W1 = (L < 4) ? W1s + L * 1024 : w15;
        const float* b1 = (L < 4) ? b1s + L * 32  : b15;
        const float* ga = (L < 4) ? g1s + L * 32  : g5;
        const float* be = (L < 4) ? be1s + L * 32 : be5;
        const float* W2 = (L < 4) ? W2s + L * 1024 : w25;
        const float* b2 = (L < 4) ? b2s + L * 32  : b25;

        layerA_k<<<NBLKA, 256, 0, stream>>>(inb, rowptr, sorted, emb, W1, b1, tb, partial, N, sBits, sentw);
        bnred1_k<<<64, 256, 0, stream>>>(partial, partial2);
        bnred2_k<<<1, 256, 0, stream>>>(partial2, ga, be, bn_ac, 1.f / (float)N);
        if (L < 4) {
            layerB32_k<<<1024, 256, 0, stream>>>(tb, bn_ac, W2, b2, outb, N);
            unsigned* tmp = inb; inb = outb; outb = tmp;
        } else {
            layerB64_k<<<1024, 256, 0, stream>>>(tb, bn_ac, W2, b2, h5w, N);
        }
    }

    // ---- pooling ----
    pool1_k<<<(N + 255) / 256, 256, 0, stream>>>(h5w, batch, maxb, sumb, N);
    final_k<<<G, 128, 0, stream>>>(maxb, sumb, batch, N, (float*)d_out);
}